// Round 1
// baseline (11135.130 us; speedup 1.0000x reference)
//
#include <hip/hip_runtime.h>
#include <stdint.h>

// ---------------------------------------------------------------------------
// LSTM_52140902973763 on MI355X (gfx950)
// Structure:
//   1) cvt fp32->bf16 of x and all weights
//   2) GEMM: Xg0 = x @ Wih0^T + (bih0+bhh0)            [8192,4096]
//   3) persistent cooperative scan kernel (256 blocks, custom grid barrier):
//      CROSS-LAYER PIPELINED: iteration i computes layer0(t=i) AND
//      layer1(t=i-1) in ONE phase -> ONE grid barrier per iteration
//      (257 barriers total vs 513 in the 2-barrier-per-step version).
//      weights live in LDS (frag-major), c-state lives in LDS, h via global.
//      Parity: ha_t -> haB[(t&1)^1], hb_t -> hbB[t&1] (initial hb seeded
//      into buffer 1).
//   4) GEMM: logits = hidden @ Wl^T + bl  -> d_out
//   5) row-wise log_softmax in-place on d_out
// Workspace use: ~268 MB.
// ---------------------------------------------------------------------------

typedef __attribute__((ext_vector_type(8))) short short8;
typedef __attribute__((ext_vector_type(4))) float floatx4;

__device__ __forceinline__ unsigned short f2bf(float f) {
  unsigned u = __float_as_uint(f);
  u += 0x7fffu + ((u >> 16) & 1u);           // round-to-nearest-even
  return (unsigned short)(u >> 16);
}

// ----------------------------- small utility kernels -----------------------

__global__ __launch_bounds__(256) void cvt_bf16_v4(const float4* __restrict__ s,
                                                   ushort4* __restrict__ d, int n4) {
  int i = blockIdx.x * 256 + threadIdx.x;
  if (i < n4) {
    float4 v = s[i];
    ushort4 o;
    o.x = f2bf(v.x); o.y = f2bf(v.y); o.z = f2bf(v.z); o.w = f2bf(v.w);
    d[i] = o;
  }
}

__global__ __launch_bounds__(256) void bias_sum2(const float* __restrict__ a0,
                                                 const float* __restrict__ b0,
                                                 float* __restrict__ o0,
                                                 const float* __restrict__ a1,
                                                 const float* __restrict__ b1,
                                                 float* __restrict__ o1) {
  int i = blockIdx.x * 256 + threadIdx.x;   // grid 16 * 256 = 4096 exactly
  o0[i] = a0[i] + b0[i];
  o1[i] = a1[i] + b1[i];
}

// ----------------------------- GEMM: C = A @ B^T + bias --------------------
// A [M,K] bf16 row-major, B [N,K] bf16 row-major, C [M,N] fp32.
// 128x128 tile, BK=32, 4 waves (2x2 of 64x64), frag-major LDS (conflict-free
// ds_read_b128). M,N multiples of 128; K multiple of 32.

__global__ __launch_bounds__(256) void gemm_bt(const unsigned short* __restrict__ A,
                                               const unsigned short* __restrict__ B,
                                               const float* __restrict__ bias,
                                               float* __restrict__ C,
                                               int M, int N, int K, int nbn) {
  __shared__ unsigned short As[128 * 32];   // frag-major: chunk (g*64+lane) -> 16B
  __shared__ unsigned short Bs[128 * 32];

  const int tid  = threadIdx.x;
  const int lane = tid & 63;
  const int wv   = tid >> 6;
  const int wm   = wv & 1;          // 64-row half of the M-tile
  const int wn   = wv >> 1;         // 64-col half of the N-tile
  const int bm   = blockIdx.x / nbn;
  const int bn   = blockIdx.x % nbn;
  const int m0   = bm * 128;
  const int n0   = bn * 128;

  const int rl  = lane & 15;
  const int kof = (lane >> 4) * 8;

  floatx4 acc[4][4];
#pragma unroll
  for (int a = 0; a < 4; ++a)
#pragma unroll
    for (int b = 0; b < 4; ++b) acc[a][b] = (floatx4){0.f, 0.f, 0.f, 0.f};

  // staging: wave wv owns chunks g = 2wv, 2wv+1 for both A and B
  unsigned short* AsW0 = As + (wv * 2 + 0) * 64 * 8;
  unsigned short* AsW1 = As + (wv * 2 + 1) * 64 * 8;
  unsigned short* BsW0 = Bs + (wv * 2 + 0) * 64 * 8;
  unsigned short* BsW1 = Bs + (wv * 2 + 1) * 64 * 8;
  const unsigned short* Ag0 = A + (size_t)(m0 + (wv * 2 + 0) * 16 + rl) * K + kof;
  const unsigned short* Ag1 = A + (size_t)(m0 + (wv * 2 + 1) * 16 + rl) * K + kof;
  const unsigned short* Bg0 = B + (size_t)(n0 + (wv * 2 + 0) * 16 + rl) * K + kof;
  const unsigned short* Bg1 = B + (size_t)(n0 + (wv * 2 + 1) * 16 + rl) * K + kof;

  const int KI = K >> 5;
  for (int kt = 0; kt < KI; ++kt) {
    short8 ra0 = *(const short8*)Ag0;
    short8 ra1 = *(const short8*)Ag1;
    short8 rb0 = *(const short8*)Bg0;
    short8 rb1 = *(const short8*)Bg1;
    Ag0 += 32; Ag1 += 32; Bg0 += 32; Bg1 += 32;
    __syncthreads();                         // prior iter's frag reads done
    *(short8*)(AsW0 + lane * 8) = ra0;
    *(short8*)(AsW1 + lane * 8) = ra1;
    *(short8*)(BsW0 + lane * 8) = rb0;
    *(short8*)(BsW1 + lane * 8) = rb1;
    __syncthreads();
    short8 af[4], bf[4];
#pragma unroll
    for (int a = 0; a < 4; ++a) af[a] = *(const short8*)(As + ((wm * 4 + a) * 64 + lane) * 8);
#pragma unroll
    for (int b = 0; b < 4; ++b) bf[b] = *(const short8*)(Bs + ((wn * 4 + b) * 64 + lane) * 8);
#pragma unroll
    for (int a = 0; a < 4; ++a)
#pragma unroll
      for (int b = 0; b < 4; ++b)
        acc[a][b] = __builtin_amdgcn_mfma_f32_16x16x32_bf16(af[a], bf[b], acc[a][b], 0, 0, 0);
  }

  const int mr = (lane >> 4) * 4;
#pragma unroll
  for (int b = 0; b < 4; ++b) {
    int col = n0 + wn * 64 + b * 16 + rl;
    float bv = bias ? bias[col] : 0.f;
#pragma unroll
    for (int a = 0; a < 4; ++a) {
      int row = m0 + wm * 64 + a * 16 + mr;
#pragma unroll
      for (int r = 0; r < 4; ++r) C[(size_t)(row + r) * N + col] = acc[a][b][r] + bv;
    }
  }
}

// ----------------------------- persistent LSTM scan ------------------------

__device__ __forceinline__ void grid_barrier(unsigned* bar, unsigned ep, unsigned nblk) {
  __syncthreads();                         // drains vmcnt: all stores in L2
  if (threadIdx.x == 0) {
    __threadfence();                       // release to device scope (L2 wb)
    __hip_atomic_fetch_add(bar, 1u, __ATOMIC_RELEASE, __HIP_MEMORY_SCOPE_AGENT);
    const unsigned target = ep * nblk;
    while (__hip_atomic_load(bar, __ATOMIC_ACQUIRE, __HIP_MEMORY_SCOPE_AGENT) < target)
      __builtin_amdgcn_s_sleep(2);
    __threadfence();                       // acquire (invalidate stale L1/L2)
  }
  __syncthreads();
}

// Block bid owns h indices [4*bid, 4*bid+4) of both layers: 16 gate rows
// per layer-matrix = {gtype*1024 + 4*bid + jj}. Weight slices in LDS in
// frag-major chunks WL[kb][lane] (16B each) -> conflict-free ds_read_b128.
//
// Pipelined schedule: iteration i (0..256) computes
//   layer0 at t=i   (i<256):  gates0 = Xg0[i] + ha_{i-1} @ Whh0^T
//   layer1 at t=i-1 (i>=1):   gates1 = b1 + ha_{i-1} @ Wih1^T + hb_{i-2} @ Whh1^T
// Both consume only state produced before the last barrier -> 1 barrier/iter.
__global__ __launch_bounds__(256) void lstm_scan(
    const unsigned short* __restrict__ WG0,    // Whh0 bf16 [4096,1024]
    const unsigned short* __restrict__ WG1i,   // Wih1 bf16
    const unsigned short* __restrict__ WG1h,   // Whh1 bf16
    const float* __restrict__ Xg0,             // [8192,4096]
    const float* __restrict__ bsum1,           // [4096]
    const float* __restrict__ h0,              // [2,32,1024]
    const float* __restrict__ c0,              // [2,32,1024]
    unsigned short* __restrict__ haB,          // [2][32*1024] bf16 (dbl buf)
    unsigned short* __restrict__ hbB,          // [2][32*1024]
    unsigned short* __restrict__ hidden,       // [256][32*1024] bf16
    float* __restrict__ hfin, float* __restrict__ cfin,
    unsigned* __restrict__ bar) {
  extern __shared__ char smem[];
  unsigned short* WL0  = (unsigned short*)smem;        // 32 KB
  unsigned short* WL1i = WL0 + 16384;                  // 32 KB
  unsigned short* WL1h = WL1i + 16384;                 // 32 KB
  float* gsum0  = (float*)(smem + 98304);              // [32][16]
  float* gwork0 = gsum0 + 512;                         // [32][16]
  float* gsum1  = gwork0 + 512;                        // [32][16]
  float* gwork1 = gsum1 + 512;                         // [32][16]
  float* cst    = gwork1 + 512;                        // [2][32][4]

  const int tid  = threadIdx.x;
  const int lane = tid & 63;
  const int wv   = tid >> 6;
  const int wm   = wv & 1;                 // batch half (m-tile)
  const int wk   = wv >> 1;                // k half / k source
  const int bid  = blockIdx.x;
  const int j0   = bid * 4;
  const int nl   = lane & 15;              // local gate row (gtype*4 + jj)
  const int kof  = (lane >> 4) * 8;
  const int grow = (nl >> 2) * 1024 + j0 + (nl & 3);   // global gate row
  const int mrow = wm * 16 + (lane >> 4) * 4;          // batch base for acc regs

  // ---- load weight slices into LDS (frag-major) ----
  for (int ci = tid; ci < 2048; ci += 256) {
    int kb = ci >> 6, ln = ci & 63;
    int n2 = ln & 15, ko = (ln >> 4) * 8;
    size_t gofs = (size_t)((n2 >> 2) * 1024 + j0 + (n2 & 3)) * 1024 + kb * 32 + ko;
    *(short8*)(WL0  + ci * 8) = *(const short8*)(WG0  + gofs);
    *(short8*)(WL1i + ci * 8) = *(const short8*)(WG1i + gofs);
    *(short8*)(WL1h + ci * 8) = *(const short8*)(WG1h + gofs);
  }
  const float b1v = bsum1[grow];

  if (tid < 128) {
    int b = tid >> 2, q = tid & 3;
    int idx = b * 1024 + j0 + q;
    cst[b * 4 + q]       = c0[idx];
    cst[128 + b * 4 + q] = c0[32768 + idx];
    haB[idx] = f2bf(h0[idx]);                 // ha_{-1} -> buffer 0
    hbB[32768 + idx] = f2bf(h0[32768 + idx]); // hb_{-1} -> buffer 1 (parity (-1)&1)
  }
  unsigned ep = 0;
  ++ep; grid_barrier(bar, ep, gridDim.x);

  for (int i = 0; i <= 256; ++i) {
    const int p = i & 1;
    const unsigned short* haR = haB + p * 32768;        // ha_{i-1}
    unsigned short*       haW = haB + (p ^ 1) * 32768;  // ha_i
    const unsigned short* hbR = hbB + p * 32768;        // hb_{i-2}
    unsigned short*       hbW = hbB + (p ^ 1) * 32768;  // hb_{i-1}
    const bool doL0 = (i < 256);
    const bool doL1 = (i > 0);

    float xg[4] = {0.f, 0.f, 0.f, 0.f};
    if (doL0 && wk == 0) {
#pragma unroll
      for (int r = 0; r < 4; ++r)
        xg[r] = Xg0[(size_t)(i * 32 + mrow + r) * 4096 + grow];
    }

    floatx4 acc0 = {0.f, 0.f, 0.f, 0.f};
    floatx4 acc1 = {0.f, 0.f, 0.f, 0.f};
    const unsigned short* aRow0 = haR + (size_t)(wm * 16 + nl) * 1024 + kof;
    const unsigned short* aRow1 = ((wk == 0) ? haR : hbR) + (size_t)(wm * 16 + nl) * 1024 + kof;
    const unsigned short* WLx   = (wk == 0) ? WL1i : WL1h;
    const int kb0 = wk * 16;

    if (doL0 && doL1) {
      // fused: 1 layer0 k-block + 2 layer1 k-blocks per u -> 12 global loads
      // in flight per unroll-4 body (latency hiding at 1 block/CU)
#pragma unroll 4
      for (int u = 0; u < 16; ++u) {
        short8 a0 = *(const short8*)(aRow0 + (kb0 + u) * 32);
        short8 w0 = *(const short8*)(WL0 + ((kb0 + u) * 64 + lane) * 8);
        short8 a1 = *(const short8*)(aRow1 + (2 * u) * 32);
        short8 w1 = *(const short8*)(WLx + ((2 * u) * 64 + lane) * 8);
        short8 a2 = *(const short8*)(aRow1 + (2 * u + 1) * 32);
        short8 w2 = *(const short8*)(WLx + ((2 * u + 1) * 64 + lane) * 8);
        acc0 = __builtin_amdgcn_mfma_f32_16x16x32_bf16(a0, w0, acc0, 0, 0, 0);
        acc1 = __builtin_amdgcn_mfma_f32_16x16x32_bf16(a1, w1, acc1, 0, 0, 0);
        acc1 = __builtin_amdgcn_mfma_f32_16x16x32_bf16(a2, w2, acc1, 0, 0, 0);
      }
    } else if (doL0) {                      // i == 0
#pragma unroll 4
      for (int kb = kb0; kb < kb0 + 16; ++kb) {
        short8 af = *(const short8*)(aRow0 + kb * 32);
        short8 bf = *(const short8*)(WL0 + (kb * 64 + lane) * 8);
        acc0 = __builtin_amdgcn_mfma_f32_16x16x32_bf16(af, bf, acc0, 0, 0, 0);
      }
    } else {                                // i == 256
#pragma unroll 4
      for (int kb = 0; kb < 32; ++kb) {
        short8 af = *(const short8*)(aRow1 + kb * 32);
        short8 bf = *(const short8*)(WLx + (kb * 64 + lane) * 8);
        acc1 = __builtin_amdgcn_mfma_f32_16x16x32_bf16(af, bf, acc1, 0, 0, 0);
      }
    }

    if (wk == 1) {
      if (doL0) {
#pragma unroll
        for (int r = 0; r < 4; ++r) gsum0[(mrow + r) * 16 + nl] = acc0[r];
      }
      if (doL1) {
#pragma unroll
        for (int r = 0; r < 4; ++r) gsum1[(mrow + r) * 16 + nl] = acc1[r];
      }
    }
    __syncthreads();
    if (wk == 0) {
      if (doL0) {
#pragma unroll
        for (int r = 0; r < 4; ++r)
          gwork0[(mrow + r) * 16 + nl] = acc0[r] + gsum0[(mrow + r) * 16 + nl] + xg[r];
      }
      if (doL1) {
#pragma unroll
        for (int r = 0; r < 4; ++r)
          gwork1[(mrow + r) * 16 + nl] = acc1[r] + gsum1[(mrow + r) * 16 + nl] + b1v;
      }
    }
    __syncthreads();

    if (tid < 128) {
      if (doL0) {                           // layer-0 cell, t = i
        int b = tid >> 2, q = tid & 3;
        float gi = gwork0[b * 16 + q];
        float gf = gwork0[b * 16 + 4 + q];
        float gg = gwork0[b * 16 + 8 + q];
        float go = gwork0[b * 16 + 12 + q];
        float iv = 1.f / (1.f + __expf(-gi));
        float fv = 1.f / (1.f + __expf(-gf));
        float gv = tanhf(gg);
        float ov = 1.f / (1.f + __expf(-go));
        float cn = fv * cst[b * 4 + q] + iv * gv;
        float hn = ov * tanhf(cn);
        cst[b * 4 + q] = cn;
        int idx = b * 1024 + j0 + q;
        haW[idx] = f2bf(hn);
        if (i == 255) { hfin[idx] = hn; cfin[idx] = cn; }
      }
    } else {
      if (doL1) {                           // layer-1 cell, t = i-1
        int tt = tid - 128;
        int b = tt >> 2, q = tt & 3;
        float gi = gwork1[b * 16 + q];
        float gf = gwork1[b * 16 + 4 + q];
        float gg = gwork1[b * 16 + 8 + q];
        float go = gwork1[b * 16 + 12 + q];
        float iv = 1.f / (1.f + __expf(-gi));
        float fv = 1.f / (1.f + __expf(-gf));
        float gv = tanhf(gg);
        float ov = 1.f / (1.f + __expf(-go));
        float cn = fv * cst[128 + b * 4 + q] + iv * gv;
        float hn = ov * tanhf(cn);
        cst[128 + b * 4 + q] = cn;
        int idx = b * 1024 + j0 + q;
        hbW[idx] = f2bf(hn);
        hidden[(size_t)(i - 1) * 32768 + idx] = f2bf(hn);
        if (i == 256) { hfin[32768 + idx] = hn; cfin[32768 + idx] = cn; }
      }
    }
    if (i < 256) { ++ep; grid_barrier(bar, ep, gridDim.x); }
    // no barrier after the last iteration: kernel completion releases all
    // writes to agent scope before the following gemm_bt launch.
  }
}

// ----------------------------- log_softmax rows ----------------------------

__device__ __forceinline__ void ols_acc(float v, float& mx, float& sm) {
  if (v <= mx) sm += __expf(v - mx);
  else { sm = sm * __expf(mx - v) + 1.f; mx = v; }
}
__device__ __forceinline__ void ols_comb(float omx, float osm, float& mx, float& sm) {
  if (omx > mx) { sm = sm * __expf(mx - omx) + osm; mx = omx; }
  else sm += osm * __expf(omx - mx);
}

__global__ __launch_bounds__(256) void logsoftmax_rows(float* __restrict__ out) {
  float* p = out + (size_t)blockIdx.x * 32000;
  const int tid = threadIdx.x;
  float mx = -3.4028235e38f, sm = 0.f;
  const float4* p4 = (const float4*)p;
  for (int i = tid; i < 8000; i += 256) {
    float4 v = p4[i];
    ols_acc(v.x, mx, sm); ols_acc(v.y, mx, sm);
    ols_acc(v.z, mx, sm); ols_acc(v.w, mx, sm);
  }
#pragma unroll
  for (int off = 32; off > 0; off >>= 1) {
    float omx = __shfl_down(mx, off);
    float osm = __shfl_down(sm, off);
    ols_comb(omx, osm, mx, sm);
  }
  __shared__ float smx[4], ssm[4], slse;
  if ((tid & 63) == 0) { smx[tid >> 6] = mx; ssm[tid >> 6] = sm; }
  __syncthreads();
  if (tid == 0) {
    for (int w = 1; w < 4; ++w) ols_comb(smx[w], ssm[w], mx, sm);
    slse = mx + __logf(sm);
  }
  __syncthreads();
  const float lse = slse;
  float4* w4 = (float4*)p;
  for (int i = tid; i < 8000; i += 256) {
    float4 v = p4[i];
    v.x -= lse; v.y -= lse; v.z -= lse; v.w -= lse;
    w4[i] = v;
  }
}

// ----------------------------- launch --------------------------------------

extern "C" void kernel_launch(void* const* d_in, const int* in_sizes, int n_in,
                              void* d_out, int out_size, void* d_ws, size_t ws_size,
                              hipStream_t stream) {
  const float* x    = (const float*)d_in[0];
  const float* h0   = (const float*)d_in[1];
  const float* c0   = (const float*)d_in[2];
  const float* Wih0 = (const float*)d_in[3];
  const float* Whh0 = (const float*)d_in[4];
  const float* bih0 = (const float*)d_in[5];
  const float* bhh0 = (const float*)d_in[6];
  const float* Wih1 = (const float*)d_in[7];
  const float* Whh1 = (const float*)d_in[8];
  const float* bih1 = (const float*)d_in[9];
  const float* bhh1 = (const float*)d_in[10];
  const float* Wl   = (const float*)d_in[11];
  const float* bl   = (const float*)d_in[12];
  float* out = (float*)d_out;

  char* ws = (char*)d_ws;
  size_t off = 0;
  auto alloc = [&](size_t bytes) -> char* {
    char* pp = ws + off;
    off += (bytes + 255) & ~(size_t)255;
    return pp;
  };
  float*          Xg0    = (float*)alloc(8192ULL * 4096 * 4);    // 134 MB
  unsigned short* xb     = (unsigned short*)alloc(8192ULL * 1024 * 2);
  unsigned short* Wihb0  = (unsigned short*)alloc(4096ULL * 1024 * 2);
  unsigned short* Whhb0  = (unsigned short*)alloc(4096ULL * 1024 * 2);
  unsigned short* Wihb1  = (unsigned short*)alloc(4096ULL * 1024 * 2);
  unsigned short* Whhb1  = (unsigned short*)alloc(4096ULL * 1024 * 2);
  unsigned short* Wlb    = (unsigned short*)alloc(32000ULL * 1024 * 2); // 65.5 MB
  unsigned short* hidden = (unsigned short*)alloc(256ULL * 32 * 1024 * 2);
  unsigned short* haB    = (unsigned short*)alloc(2ULL * 32 * 1024 * 2);
  unsigned short* hbB    = (unsigned short*)alloc(2ULL * 32 * 1024 * 2);
  float*          bsum0  = (float*)alloc(4096 * 4);
  float*          bsum1  = (float*)alloc(4096 * 4);
  unsigned*       bar    = (unsigned*)alloc(256);
  float* hfin = out + 262144000;
  float* cfin = hfin + 65536;
  (void)in_sizes; (void)n_in; (void)out_size; (void)ws_size;

  hipMemsetAsync(bar, 0, 16, stream);

  // fp32 -> bf16 conversions
  cvt_bf16_v4<<<8192, 256, 0, stream>>>((const float4*)x, (ushort4*)xb, 2097152);
  cvt_bf16_v4<<<4096, 256, 0, stream>>>((const float4*)Wih0, (ushort4*)Wihb0, 1048576);
  cvt_bf16_v4<<<4096, 256, 0, stream>>>((const float4*)Whh0, (ushort4*)Whhb0, 1048576);
  cvt_bf16_v4<<<4096, 256, 0, stream>>>((const float4*)Wih1, (ushort4*)Wihb1, 1048576);
  cvt_bf16_v4<<<4096, 256, 0, stream>>>((const float4*)Whh1, (ushort4*)Whhb1, 1048576);
  cvt_bf16_v4<<<32000, 256, 0, stream>>>((const float4*)Wl, (ushort4*)Wlb, 8192000);
  bias_sum2<<<16, 256, 0, stream>>>(bih0, bhh0, bsum0, bih1, bhh1, bsum1);

  // Xg0 = x @ Wih0^T + bsum0
  gemm_bt<<<64 * 32, 256, 0, stream>>>(xb, Wihb0, bsum0, Xg0, 8192, 4096, 1024, 32);

  // persistent recurrent scan: 256 blocks (1/CU by LDS), custom grid barrier
  // LDS: 96 KB weights + gsum0/gwork0/gsum1/gwork1 (4x2 KB) + cst (1 KB)
  hipFuncSetAttribute((const void*)lstm_scan,
                      hipFuncAttributeMaxDynamicSharedMemorySize, 107520);
  lstm_scan<<<256, 256, 107520, stream>>>(Whhb0, Wihb1, Whhb1, Xg0, bsum1, h0, c0,
                                          haB, hbB, hidden, hfin, cfin, bar);

  // logits = hidden @ Wl^T + bl
  gemm_bt<<<64 * 250, 256, 0, stream>>>(hidden, Wlb, bl, out, 8192, 32000, 1024, 250);

  // in-place log_softmax per row
  logsoftmax_rows<<<8192, 256, 0, stream>>>(out);
}